// Round 9
// baseline (153.393 us; speedup 1.0000x reference)
//
#include <hip/hip_runtime.h>
#include <hip/hip_bf16.h>
#include <cmath>

#define NB   4
#define NS   1024
#define NHID 1024
#define NH   16
#define NDH  64
#define QKV_PLANE (NB * NH * NS * NDH)   // elements per q/k/v plane

typedef __attribute__((ext_vector_type(8))) short bf16x8;
typedef __attribute__((ext_vector_type(4))) short bf16x4;
typedef __attribute__((ext_vector_type(4))) float f32x4;
typedef __attribute__((ext_vector_type(8))) unsigned short u16x8;

#if __has_builtin(__builtin_amdgcn_mfma_f32_16x16x16bf16_1k)
#define MFMA16 1
#else
#define MFMA16 0
#endif

typedef __attribute__((address_space(1))) const void gv_t;
typedef __attribute__((address_space(3))) void       lv_t;

__device__ __forceinline__ void gload16(const void* g, void* l) {
    // async global->LDS, 16B/lane; LDS dest = wave-uniform base + lane*16,
    // global address is per-lane arbitrary (lets us swizzle the LDS layout).
    __builtin_amdgcn_global_load_lds((gv_t*)g, (lv_t*)l, 16, 0, 0);
}

__device__ __forceinline__ unsigned short f2b(float f) {
    union { float f; unsigned int u; } v; v.f = f;
    unsigned int r = (v.u + 0x7fff + ((v.u >> 16) & 1)) >> 16;   // RNE
    return (unsigned short)r;
}

// packed fp32x2 -> bf16x2 (RNE); lo 16 bits = a
__device__ __forceinline__ unsigned int f2b2(float a, float b) {
    __hip_bfloat162 h = __float22bfloat162_rn(make_float2(a, b));
    union { __hip_bfloat162 h; unsigned int u; } v; v.h = h;
    return v.u;
}

__device__ __forceinline__ float fexp2(float x) {
#if __has_builtin(__builtin_amdgcn_exp2f)
    return __builtin_amdgcn_exp2f(x);
#else
    return exp2f(x);
#endif
}

// counted vmcnt wait (keeps prefetch loads in flight) + scheduling fence
#define VMWAIT(N) do { \
    asm volatile("s_waitcnt vmcnt(" #N ")" ::: "memory"); \
    __builtin_amdgcn_sched_barrier(0); } while (0)

// raw barrier (no implicit vmcnt(0) drain, unlike __syncthreads)
#define SBAR() do { \
    __builtin_amdgcn_sched_barrier(0); \
    __builtin_amdgcn_s_barrier(); \
    __builtin_amdgcn_sched_barrier(0); } while (0)

// ---------------------------------------------------------------------------
// Prep (single launch, grid (16,16,5)):
//  z<3 : cast+transpose Wq/Wk/Wv [K][N] fp32 -> wt [z*1024+n][k] bf16
//  z==3: cast hidden_states fp32 -> bf16 row-major [4096][1024]
//  z==4: RoPE table cs[s][d] = (cos,sin)(freqs[s][d]), d<32  (float2[1024][32])
// ---------------------------------------------------------------------------
__global__ __launch_bounds__(256) void prep_kernel(
    const float* __restrict__ hs, const float* __restrict__ freqs,
    const float* __restrict__ Wq, const float* __restrict__ Wk,
    const float* __restrict__ Wv,
    unsigned short* __restrict__ hsb, unsigned short* __restrict__ wt,
    float2* __restrict__ cs)
{
    const int z   = blockIdx.z;
    const int tid = threadIdx.x;

    if (z == 3) {                    // cast hs: 256 blocks x 16384 elements
        const int bx = blockIdx.y * 16 + blockIdx.x;
        #pragma unroll
        for (int c = 0; c < 16; ++c) {
            const int idx = bx * 16384 + (c * 256 + tid) * 4;
            float4 v = *(const float4*)&hs[idx];
            ushort4 o;
            o.x = f2b(v.x); o.y = f2b(v.y); o.z = f2b(v.z); o.w = f2b(v.w);
            *(ushort4*)&hsb[idx] = o;
        }
        return;
    }
    if (z == 4) {                    // rope table: 128 blocks x 256 entries
        const int bx = blockIdx.y * 16 + blockIdx.x;
        if (bx < 128) {
            const int id = bx * 256 + tid;     // 0..32767
            const int s = id >> 5, d = id & 31;
            const float ang = freqs[s * NDH + d];
            float sn, cn;
            sincosf(ang, &sn, &cn);
            cs[id] = make_float2(cn, sn);
        }
        return;
    }

    // wt transpose
    const float* __restrict__ W = (z == 0) ? Wq : (z == 1) ? Wk : Wv;
    __shared__ float t[64][65];
    const int k0 = blockIdx.x * 64, n0 = blockIdx.y * 64;
    #pragma unroll
    for (int c = 0; c < 16; ++c) {
        const int flat = c * 256 + tid;
        const int r = flat >> 6, cc = flat & 63;
        t[r][cc] = W[(size_t)(k0 + r) * NHID + n0 + cc];
    }
    __syncthreads();
    #pragma unroll
    for (int c = 0; c < 16; ++c) {
        const int flat = c * 256 + tid;
        const int r = flat >> 6, cc = flat & 63;
        wt[(size_t)(z * 1024 + n0 + r) * NHID + k0 + cc] = f2b(t[cc][r]);
    }
}

// ---------------------------------------------------------------------------
// Fused GEMM, bf16 MFMA, 128x128 tile, 256 thr (4 waves, 64x64 acc each).
// K-loop: BK=32, 3-slot rotating LDS pipeline, COUNTED vmcnt (T3/T4): stage
// tile t+2 at top of iteration t, compute tile t, vmcnt(4) certifies tile
// t+1 while t+2's loads stay in flight ACROSS the raw barrier. No vmcnt(0)
// drain in the loop. LDS 48 KB -> 3 blocks/CU.  (UNCHANGED — control;
// R7's 50.5us was shown environmental by R8's byte-identical rerun.)
// tx < 16 : q/k tiles  C = HS . W^T  (fused bias + table-RoPE)
// tx >= 16: v^T tiles  C = Wv^T . HS^T (fused bias), V stored [b][h][d][s].
// XCD-rectangle swizzle kept from R2 (FETCH 42->35 MB measured).
// ---------------------------------------------------------------------------
__global__ __launch_bounds__(256) void fused_gemm_kernel(
    const unsigned short* __restrict__ hsb,   // [4096][1024] bf16
    const unsigned short* __restrict__ wt,    // [3072][1024] bf16  ([n][k])
    const float2* __restrict__ cs,            // [1024][32] (cos,sin)
    const float* __restrict__ bq, const float* __restrict__ bk,
    const float* __restrict__ bv,
    unsigned short* __restrict__ qkv)
{
    __shared__ short SH[24576];      // 48 KB: 3 slots x (A[128][32] | B[128][32])
                                     // epilogue reuses [0,16896) as E[128][132]

    const int tid  = threadIdx.x;
    const int lane = tid & 63;
    const int wv   = __builtin_amdgcn_readfirstlane(tid >> 6);   // 0..3

    // ---- XCD-rectangle swizzle: dispatch-linear -> (tx,ty) ----
    const int hw  = blockIdx.x + 24 * blockIdx.y;   // 0..767, xcd ~ hw%8
    const int xcd = hw & 7;
    const int j   = hw >> 3;                        // 0..95 within XCD
    const int tx  = (xcd & 1) * 12 + (j % 12);      // 0..23
    const int ty  = (xcd >> 1) * 8 + (j / 12);      // 0..31

    const bool vmode = (tx >= 16);

    const unsigned short* Amat;
    const unsigned short* Bmat;
    int a_base, b_base, m0, n0, vb_ = 0;
    if (!vmode) {
        n0 = tx * 128;                       // 0..2047 (q,k planes)
        m0 = ty * 128;                       // hs rows
        Amat = hsb;  a_base = m0;
        Bmat = wt;   b_base = n0;
    } else {
        m0  = (tx - 16) * 128;               // v-channel rows 0..1023
        vb_ = ty >> 3;                       // batch
        n0  = (ty & 7) * 128;                // s
        Amat = wt;   a_base = 2048 + m0;
        Bmat = hsb;  b_base = vb_ * 1024 + n0;
    }

    // ---- staging addressing: wave wv covers rows {16wv..16wv+15, +64} of
    //      A and B per tile. lane i -> row (i>>2); global k-chunk is
    //      pre-swizzled: c = (i&3) ^ ((i>>3)&3)  (LDS dest stays linear).
    const int srow = lane >> 2;                          // 0..15
    const int skc  = ((lane & 3) ^ ((lane >> 3) & 3)) * 8;
    const unsigned short* gA1 = Amat + (size_t)(a_base + 16 * wv + srow) * NHID + skc;
    const unsigned short* gA2 = gA1 + (size_t)64 * NHID;
    const unsigned short* gB1 = Bmat + (size_t)(b_base + 16 * wv + srow) * NHID + skc;
    const unsigned short* gB2 = gB1 + (size_t)64 * NHID;

    // slot layout (shorts): slot*8192 + [A: row*32 + c'*8 | B: 4096 + ...]
#define STAGE(S, T) do { \
    short* Sb_ = SH + (S) * 8192 + 512 * wv; \
    const size_t ko_ = (size_t)(T) * 32; \
    gload16(gA1 + ko_, Sb_); \
    gload16(gA2 + ko_, Sb_ + 2048); \
    gload16(gB1 + ko_, Sb_ + 4096); \
    gload16(gB2 + ko_, Sb_ + 6144); \
} while (0)

    // ---- fragment read addresses ----
    const int R  = (wv & 1) * 64;
    const int CW = (wv >> 1) * 64;
    const int c0 = lane & 15;
    const int g  = lane >> 4;
    const int swz  = (g ^ ((c0 >> 1) & 3)) * 8;    // chunk swizzle (shorts)
    const int aofl = (R + c0) * 32 + swz;
    const int bofl = 4096 + (CW + c0) * 32 + swz;

    f32x4 acc[4][4] = {};

#define COMP(S) do { \
    const short* Sc_ = SH + (S) * 8192; \
    bf16x8 af[4], bfr[4]; \
    _Pragma("unroll") \
    for (int i_ = 0; i_ < 4; ++i_) af[i_]  = *(const bf16x8*)&Sc_[aofl + 512 * i_]; \
    _Pragma("unroll") \
    for (int j_ = 0; j_ < 4; ++j_) bfr[j_] = *(const bf16x8*)&Sc_[bofl + 512 * j_]; \
    __builtin_amdgcn_s_setprio(1); \
    _Pragma("unroll") \
    for (int i_ = 0; i_ < 4; ++i_) \
        _Pragma("unroll") \
        for (int j_ = 0; j_ < 4; ++j_) \
            acc[i_][j_] = __builtin_amdgcn_mfma_f32_16x16x32_bf16( \
                af[i_], bfr[j_], acc[i_][j_], 0, 0, 0); \
    __builtin_amdgcn_s_setprio(0); \
} while (0)

    // ---- K-loop: 32 tiles of BK=32, 3-slot rotation, counted vmcnt ----
    STAGE(0, 0);
    STAGE(1, 1);
    VMWAIT(4);                       // tile 0 landed (tile 1's 4 in flight)
    SBAR();

    #pragma unroll 1
    for (int tb = 0; tb < 30; tb += 3) {
        STAGE(2, tb + 2); COMP(0); VMWAIT(4); SBAR();   // t = tb
        STAGE(0, tb + 3); COMP(1); VMWAIT(4); SBAR();   // t = tb+1
        STAGE(1, tb + 4); COMP(2); VMWAIT(4); SBAR();   // t = tb+2
    }
    // t = 30 (slot 0): nothing left to stage; certify tile 31
    COMP(0); VMWAIT(0); SBAR();
    // t = 31 (slot 1)
    COMP(1);
#undef STAGE
#undef COMP

    // ---- epilogue: compute (bit-identical), restage via LDS [128][132] ----
    __syncthreads();                 // all waves done reading slots
    unsigned short* E = (unsigned short*)SH;
    const int qrow4 = g * 4;

    if (!vmode) {
        const int z  = n0 >> 10;
        const int hd = ((n0 & 1023) + CW) >> 6;
        const float* __restrict__ bb = (z == 0) ? bq : bk;
        const float b0 = bb[hd * 64 + c0];
        const float b1 = bb[hd * 64 + c0 + 16];
        const float b2 = bb[hd * 64 + c0 + 32];
        const float b3 = bb[hd * 64 + c0 + 48];

        #pragma unroll
        for (int i = 0; i < 4; ++i) {
            #pragma unroll
            for (int r = 0; r < 4; ++r) {
                const int ml = R + qrow4 + 16 * i + r;      // local row
                const int s  = (m0 + ml) & 1023;
                float o0 = acc[i][0][r] + b0;
                float o1 = acc[i][1][r] + b1;
                float o2 = acc[i][2][r] + b2;
                float o3 = acc[i][3][r] + b3;
                const float2 cs0 = cs[s * 32 + c0];
                const float2 cs1 = cs[s * 32 + c0 + 16];
                unsigned short* e = E + ml * 132 + CW + c0;
                e[0]  = f2b(o0 * cs0.x - o2 * cs0.y);
                e[16] = f2b(o1 * cs1.x - o3 * cs1.y);
                e[32] = f2b(o2 * cs0.x + o0 * cs0.y);
                e[48] = f2b(o3 * cs1.x + o1 * cs1.y);
            }
        }
        __syncthreads();             // E complete

        const int hd0 = (n0 & 1023) >> 6;
        unsigned short* __restrict__ base = qkv + (size_t)z * QKV_PLANE;
        #pragma unroll
        for (int c = 0; c < 8; ++c) {
            const int chunk = c * 256 + tid;   // 0..2047
            const int row   = chunk >> 4;      // local m
            const int col16 = chunk & 15;      // 16B chunk within row
            const int m     = m0 + row;
            const int bidx  = m >> 10;
            const int s     = m & 1023;
            const int head  = hd0 + (col16 >> 3);
            const int d     = (col16 & 7) * 8;
            u16x8 v = *(const u16x8*)&E[row * 132 + col16 * 8];
            *(u16x8*)&base[(((size_t)bidx * NH + head) * NS + s) * NDH + d] = v;
        }
    } else {
        #pragma unroll
        for (int i = 0; i < 4; ++i) {
            #pragma unroll
            for (int r = 0; r < 4; ++r) {
                const int ml  = R + qrow4 + 16 * i + r;     // local d-channel
                const float bvm = bv[m0 + ml];
                unsigned short* e = E + ml * 132 + CW + c0;
                e[0]  = f2b(acc[i][0][r] + bvm);
                e[16] = f2b(acc[i][1][r] + bvm);
                e[32] = f2b(acc[i][2][r] + bvm);
                e[48] = f2b(acc[i][3][r] + bvm);
            }
        }
        __syncthreads();             // E complete

        unsigned short* __restrict__ vplane = qkv + 2 * (size_t)QKV_PLANE;
        #pragma unroll
        for (int c = 0; c < 8; ++c) {
            const int chunk = c * 256 + tid;
            const int row   = chunk >> 4;      // local d-channel
            const int col16 = chunk & 15;      // s chunk
            u16x8 v = *(const u16x8*)&E[row * 132 + col16 * 8];
            *(u16x8*)&vplane[((size_t)(vb_ * 1024 + m0 + row)) * NS
                             + n0 + col16 * 8] = v;
        }
    }
}

// ---------------------------------------------------------------------------
// Flash attention, bf16 MFMA. Block = 512 thr (8 waves), Q-tile 128 rows of
// one (b,h); wave w owns qrows [w*16, w*16+16). K-tile 64 keys.
// grid 512 blocks -> 2 blocks/CU = 16 waves/CU. 3-slot K/V pipeline with
// counted vmcnt + setprio + XCD swizzle + register-mask (kept).
//
// ROUND CHANGE: remove the P LDS round-trip entirely. The x32 PV A-fragment
// needs keys 8g..8g+7 (not lane-resident), but the 16x16x16 MFMA A-fragment
// needs keys 4g+j per 16-block — EXACTLY what each lane holds from the
// swapped QK^T output (S^T: q=lane&15, keys 4g+r+16mt). So PV becomes
// 4 mt-blocks x 4 d-tiles of mfma_f32_16x16x16bf16_1k with P straight from
// registers (same 8 cvt_pk as before, zero DS, zero cross-lane). V B-operand
// = 16 ds_read_b64 (vs 8 b128; same LDS BW, even bank spread under the
// existing swizzle: LDS chunk = Kc ^ (d&7), within-chunk 4*(g&1)). Saves
// 4 b64 writes + 2 b128 reads per wave-tile (-18% DS) and kills the per-tile
// P write->read latency chain; PsA deleted (LDS 64.5 -> 48.5 KB). PV k-order
// re-associates (4x16 vs 2x32) — delta well under the bf16 quantization
// floor. Fallback to the PsA path if the builtin is unavailable.
// ---------------------------------------------------------------------------
__global__ __launch_bounds__(512) void attn_kernel(
    const unsigned short* __restrict__ qkv, const float* __restrict__ mask,
    float* __restrict__ out)
{
    // ---- XCD swizzle: dispatch-linear -> (qt, h, b) ----
    const int hw  = blockIdx.x + 8 * (blockIdx.y + 16 * blockIdx.z); // 0..511
    const int xcd = hw & 7;
    const int j   = hw >> 3;             // 0..63 within XCD
    const int hb  = xcd * 8 + (j & 7);   // 0..63: 8 (b,h) pairs per XCD
    const int qt  = j >> 3;              // 0..7
    const int h   = hb & 15, b = hb >> 4;

    const unsigned short* qp  = qkv + ((size_t)(b * NH + h) * NS) * NDH;      // [s][d]
    const unsigned short* kp  = qp + QKV_PLANE;                               // [s][d]
    const unsigned short* vtp = qkv + 2 * (size_t)QKV_PLANE
                              + ((size_t)(b * NH + h) * NDH) * NS;            // [d][s]

    __shared__ unsigned short KsA[3][64 * 64]; // 3x8 KB swizzled [key][dchunk]
    __shared__ unsigned short VtA[3][64 * 64]; // 3x8 KB swizzled [d][keychunk]
#if !MFMA16
    __shared__ unsigned short PsA[128 * 64];   // 16 KB swizzled [qrow][keychunk]
#endif
    __shared__ float Ll[128];                  // row sums

    const int tid  = threadIdx.x;
    const int lane = tid & 63;
    const int w    = __builtin_amdgcn_readfirstlane(tid >> 6);   // 0..7
    const int c0   = lane & 15;
    const int g    = lane >> 4;          // 0..3
    const int sw7  = c0 & 7;
    const float C1 = 0.125f * 1.44269504f;
    const float L2E = 1.44269504f;
    const float* __restrict__ mrow = mask + (size_t)b * NS;

    // ---- ktmax probe load (issued first; retired by the ballot below) ----
    float mval = -2.0f;
    if (lane < 16) mval = mrow[lane * 64];

    // ---- Q fragments (B-operand, loop-invariant), qrow = qt*128+w*16+c0 ----
    bf16x8 qf[2];
    #pragma unroll
    for (int ks = 0; ks < 2; ++ks)
        qf[ks] = *(const bf16x8*)&qp[
            (size_t)(qt * 128 + w * 16 + c0) * NDH + g * 8 + ks * 32];

    // ---- staging: wave w stages K chunk w and V chunk w (1 KB each) ----
    const int i8 = lane >> 3, c8 = lane & 7;
    const int gsw = (c8 ^ i8) * 8;                   // swizzled element offset
    const unsigned short* gk0 = kp  + (size_t)(w * 8 + i8) * NDH + gsw;
    const unsigned short* gv0 = vtp + (size_t)(w * 8 + i8) * NS  + gsw;

    // ---- loop-invariant LDS addresses (shorts) ----
    int kaddr[4][2];
    #pragma unroll
    for (int mt = 0; mt < 4; ++mt)
        #pragma unroll
        for (int ks = 0; ks < 2; ++ks)
            kaddr[mt][ks] = (mt * 16 + c0) * 64 + ((g + ks * 4) ^ sw7) * 8;
#if MFMA16
    // V b64 read: keys {16mt+4g..+3} at d-row (nd*16+c0):
    // addr = (nd*16+c0)*64 + ((2mt+(g>>1)) ^ sw7)*8 + (g&1)*4
    int vk[4];
    #pragma unroll
    for (int mt = 0; mt < 4; ++mt)
        vk[mt] = ((2 * mt + (g >> 1)) ^ sw7) * 8 + (g & 1) * 4;
    const int vrow = c0 * 64;
#else
    int pw4[4], pr[2];
    #pragma unroll
    for (int mt = 0; mt < 4; ++mt)
        pw4[mt] = (w * 16 + c0) * 64 + ((2 * mt + (g >> 1)) ^ sw7) * 8 + (g & 1) * 4;
    #pragma unroll
    for (int ks = 0; ks < 2; ++ks)
        pr[ks] = (w * 16 + c0) * 64 + ((g + ks * 4) ^ sw7) * 8;
#endif

    // ---- prologue: stage tiles 0,1 into slots 0,1 (tile 1 memory is always
    //      valid: full NS keys allocated; harmless if ktmax==1) ----
    gload16(gk0,                &KsA[0][w * 512]);
    gload16(gv0,                &VtA[0][w * 512]);
    gload16(gk0 + 64 * NDH,     &KsA[1][w * 512]);
    gload16(gv0 + 64,           &VtA[1][w * 512]);

    // ---- uniform tile bound (mask monotone): #tiles whose first key is
    //      unmasked. Ballot waits the probe load (oldest) at vmcnt(4). ----
    int ktmax = __popcll(__ballot(mval >= -1.0f));
    if (ktmax < 1) ktmax = 1;

    VMWAIT(2);                       // tile 0 landed (tile 1's 2 in flight)
    SBAR();

    float lrow = 0.f;
    f32x4 O[4] = {};

    int sl = 0;                              // slot of tile kt
    for (int kt = 0; kt < ktmax; ++kt) {
        const bool more1 = (kt + 1 < ktmax);
        const bool more2 = (kt + 2 < ktmax);

        // ---- mask prefetch for THIS tile: 4 global float4 -> registers,
        //      issued oldest this iteration (sched_barrier pins order) ----
        float4 mkf[4];
        #pragma unroll
        for (int mt = 0; mt < 4; ++mt)
            mkf[mt] = *(const float4*)&mrow[kt * 64 + mt * 16 + g * 4];
        __builtin_amdgcn_sched_barrier(0);

        // ---- issue tile kt+2 stage into slot (sl+2)%3 (async) ----
        if (more2) {
            const int s2 = (sl >= 1) ? sl - 1 : sl + 2;    // (sl+2)%3
            gload16(gk0 + (size_t)(kt + 2) * 64 * NDH, &KsA[s2][w * 512]);
            gload16(gv0 + (size_t)(kt + 2) * 64,       &VtA[s2][w * 512]);
        }

        const unsigned short* Kb = KsA[sl];
        const unsigned short* Vb = VtA[sl];

        // ---- S^T = K . Q^T  (8 MFMA) ----
        bf16x8 kf[4][2];
        #pragma unroll
        for (int mt = 0; mt < 4; ++mt)
            #pragma unroll
            for (int ks = 0; ks < 2; ++ks)
                kf[mt][ks] = *(const bf16x8*)&Kb[kaddr[mt][ks]];
        f32x4 S[4];
        __builtin_amdgcn_s_setprio(1);
        #pragma unroll
        for (int mt = 0; mt < 4; ++mt) {
            f32x4 a = {};
            a = __builtin_amdgcn_mfma_f32_16x16x32_bf16(kf[mt][0], qf[0], a, 0, 0, 0);
            a = __builtin_amdgcn_mfma_f32_16x16x32_bf16(kf[mt][1], qf[1], a, 0, 0, 0);
            S[mt] = a;
        }
        __builtin_amdgcn_s_setprio(0);

        // ---- softmax numerator: p = exp2(S*C1 + m*log2e) ----
        float psum = 0.f;
#if MFMA16
        bf16x4 pa[4];
#endif
        #pragma unroll
        for (int mt = 0; mt < 4; ++mt) {
            float p0 = fexp2(S[mt][0] * C1 + mkf[mt].x * L2E);
            float p1 = fexp2(S[mt][1] * C1 + mkf[mt].y * L2E);
            float p2 = fexp2(S[mt][2] * C1 + mkf[mt].z * L2E);
            float p3 = fexp2(S[mt][3] * C1 + mkf[mt].w * L2E);
            psum += (p0 + p1) + (p2 + p3);
            union { uint2 u; bf16x4 v; } cv;
            cv.u.x = f2b2(p0, p1);
            cv.u.y = f2b2(p2, p3);
#if MFMA16
            pa[mt] = cv.v;                 // P stays in registers
#else
            *(uint2*)&PsA[pw4[mt]] = cv.u; // ds_write_b64, wave-private row
#endif
        }
        lrow += psum;

        // ---- O += P . V ----
#if MFMA16
        // 16 x (16x16x16): A = pa[mt] (keys 4g+j+16mt, lane-resident),
        // B = V[keys][d] via b64 reads from VtA[d][keychunk].
        __builtin_amdgcn_s_setprio(1);
        #pragma unroll
        for (int nd = 0; nd < 4; ++nd) {
            f32x4 o = O[nd];
            #pragma unroll
            for (int mt = 0; mt < 4; ++mt) {
                bf16x4 vb = *(const bf16x4*)&Vb[vrow + nd * 1024 + vk[mt]];
                o = __builtin_amdgcn_mfma_f32_16x16x16bf16_1k(pa[mt], vb, o, 0, 0, 0);
            }
            O[nd] = o;
        }
        __builtin_amdgcn_s_setprio(0);
#else
        bf16x8 pf[2], vf[4][2];
        #pragma unroll
        for (int ks = 0; ks < 2; ++ks)
            pf[ks] = *(const bf16x8*)&PsA[pr[ks]];
        #pragma unroll
        for (int nd = 0; nd < 4; ++nd)
            #pragma unroll
            for (int ks = 0; ks < 2; ++ks)
                vf[nd][ks] = *(const bf16x8*)&Vb[kaddr[nd][ks]];
        __builtin_amdgcn_s_setprio(1);
        #pragma unroll
        for (int nd = 0; nd < 4; ++nd) {
            f32x4 o = O[nd];
            o = __builtin_amdgcn_mfma_f32_16x16x32_bf16(pf[0], vf[nd][0], o, 0, 0, 0);
            o = __builtin_amdgcn_mfma_f32_16x16x32_bf16(pf[1], vf[nd][1], o, 0, 0, 0);
            O[nd] = o;
        }
        __builtin_amdgcn_s_setprio(0);
#endif

        // ---- counted certify + raw barrier (no full drain in the loop) ----
        if (more1) {
            if (more2) { VMWAIT(2); }    // tile kt+1 landed; kt+2 in flight
            else       { VMWAIT(0); }    // nothing issued this iter: drain
            SBAR();                      // all waves: slot reuse + visibility
        }
        sl = (sl == 2) ? 0 : sl + 1;
    }

    // ---- final l reduction + normalize + store ----
    lrow += __shfl_xor(lrow, 16);
    lrow += __shfl_xor(lrow, 32);
    if (g == 0) Ll[w * 16 + c0] = lrow;    // same-wave LDS, no barrier needed
    float4 lv4 = *(const float4*)&Ll[w * 16 + g * 4];
    float inv[4];
    #pragma unroll
    for (int r = 0; r < 4; ++r) inv[r] = 1.0f / ((const float*)&lv4)[r];

    #pragma unroll
    for (int nd = 0; nd < 4; ++nd)
        #pragma unroll
        for (int r = 0; r < 4; ++r) {
            const int row = qt * 128 + w * 16 + g * 4 + r;
            const int col = h * 64 + nd * 16 + c0;
            out[((size_t)b * NS + row) * NHID + col] = O[nd][r] * inv[r];
        }
}

// ---------------------------------------------------------------------------
extern "C" void kernel_launch(void* const* d_in, const int* in_sizes, int n_in,
                              void* d_out, int out_size, void* d_ws, size_t ws_size,
                              hipStream_t stream) {
    const float* hs    = (const float*)d_in[0];
    const float* mask  = (const float*)d_in[1];
    const float* freqs = (const float*)d_in[2];
    const float* Wq    = (const float*)d_in[3];
    const float* bq    = (const float*)d_in[4];
    const float* Wk    = (const float*)d_in[5];
    const float* bk    = (const float*)d_in[6];
    const float* Wv    = (const float*)d_in[7];
    const float* bv    = (const float*)d_in[8];
    float* out = (float*)d_out;

    // workspace: qkv bf16 25.2MB | hsb bf16 8.4MB | wt bf16 6.3MB | cs 256KB
    char* ws = (char*)d_ws;
    unsigned short* qkvb = (unsigned short*)ws;
    unsigned short* hsb  = (unsigned short*)(ws + 25165824);
    unsigned short* wtb  = (unsigned short*)(ws + 33554432);
    float2*         csb  = (float2*)       (ws + 39845888);

    prep_kernel<<<dim3(16, 16, 5), 256, 0, stream>>>(hs, freqs, Wq, Wk, Wv,
                                                     hsb, wtb, csb);
    fused_gemm_kernel<<<dim3(24, 32), 256, 0, stream>>>(hsb, wtb, csb,
                                                        bq, bk, bv, qkvb);
    attn_kernel<<<dim3(NS / 128, NH, NB), 512, 0, stream>>>(qkvb, mask, out);
}

// Round 10
// 146.070 us; speedup vs baseline: 1.0501x; 1.0501x over previous
//
#include <hip/hip_runtime.h>
#include <hip/hip_bf16.h>
#include <cmath>

#define NB   4
#define NS   1024
#define NHID 1024
#define NH   16
#define NDH  64
#define QKV_PLANE (NB * NH * NS * NDH)   // elements per q/k/v plane

typedef __attribute__((ext_vector_type(8))) short bf16x8;
typedef __attribute__((ext_vector_type(4))) float f32x4;
typedef __attribute__((ext_vector_type(8))) unsigned short u16x8;

typedef __attribute__((address_space(1))) const void gv_t;
typedef __attribute__((address_space(3))) void       lv_t;

__device__ __forceinline__ void gload16(const void* g, void* l) {
    // async global->LDS, 16B/lane; LDS dest = wave-uniform base + lane*16,
    // global address is per-lane arbitrary (lets us swizzle the LDS layout).
    __builtin_amdgcn_global_load_lds((gv_t*)g, (lv_t*)l, 16, 0, 0);
}

__device__ __forceinline__ unsigned short f2b(float f) {
    union { float f; unsigned int u; } v; v.f = f;
    unsigned int r = (v.u + 0x7fff + ((v.u >> 16) & 1)) >> 16;   // RNE
    return (unsigned short)r;
}

// packed fp32x2 -> bf16x2 (RNE); lo 16 bits = a
__device__ __forceinline__ unsigned int f2b2(float a, float b) {
    __hip_bfloat162 h = __float22bfloat162_rn(make_float2(a, b));
    union { __hip_bfloat162 h; unsigned int u; } v; v.h = h;
    return v.u;
}

__device__ __forceinline__ float fexp2(float x) {
#if __has_builtin(__builtin_amdgcn_exp2f)
    return __builtin_amdgcn_exp2f(x);
#else
    return exp2f(x);
#endif
}

// counted vmcnt wait (keeps prefetch loads in flight) + scheduling fence
#define VMWAIT(N) do { \
    asm volatile("s_waitcnt vmcnt(" #N ")" ::: "memory"); \
    __builtin_amdgcn_sched_barrier(0); } while (0)

// raw barrier (no implicit vmcnt(0) drain, unlike __syncthreads)
#define SBAR() do { \
    __builtin_amdgcn_sched_barrier(0); \
    __builtin_amdgcn_s_barrier(); \
    __builtin_amdgcn_sched_barrier(0); } while (0)

// ---------------------------------------------------------------------------
// Prep (single launch, grid (16,16,5)):
//  z<3 : cast+transpose Wq/Wk/Wv [K][N] fp32 -> wt [z*1024+n][k] bf16
//  z==3: cast hidden_states fp32 -> bf16 row-major [4096][1024]
//  z==4: RoPE table cs[s][d] = (cos,sin)(freqs[s][d]), d<32  (float2[1024][32])
// ---------------------------------------------------------------------------
__global__ __launch_bounds__(256) void prep_kernel(
    const float* __restrict__ hs, const float* __restrict__ freqs,
    const float* __restrict__ Wq, const float* __restrict__ Wk,
    const float* __restrict__ Wv,
    unsigned short* __restrict__ hsb, unsigned short* __restrict__ wt,
    float2* __restrict__ cs)
{
    const int z   = blockIdx.z;
    const int tid = threadIdx.x;

    if (z == 3) {                    // cast hs: 256 blocks x 16384 elements
        const int bx = blockIdx.y * 16 + blockIdx.x;
        #pragma unroll
        for (int c = 0; c < 16; ++c) {
            const int idx = bx * 16384 + (c * 256 + tid) * 4;
            float4 v = *(const float4*)&hs[idx];
            ushort4 o;
            o.x = f2b(v.x); o.y = f2b(v.y); o.z = f2b(v.z); o.w = f2b(v.w);
            *(ushort4*)&hsb[idx] = o;
        }
        return;
    }
    if (z == 4) {                    // rope table: 128 blocks x 256 entries
        const int bx = blockIdx.y * 16 + blockIdx.x;
        if (bx < 128) {
            const int id = bx * 256 + tid;     // 0..32767
            const int s = id >> 5, d = id & 31;
            const float ang = freqs[s * NDH + d];
            float sn, cn;
            sincosf(ang, &sn, &cn);
            cs[id] = make_float2(cn, sn);
        }
        return;
    }

    // wt transpose
    const float* __restrict__ W = (z == 0) ? Wq : (z == 1) ? Wk : Wv;
    __shared__ float t[64][65];
    const int k0 = blockIdx.x * 64, n0 = blockIdx.y * 64;
    #pragma unroll
    for (int c = 0; c < 16; ++c) {
        const int flat = c * 256 + tid;
        const int r = flat >> 6, cc = flat & 63;
        t[r][cc] = W[(size_t)(k0 + r) * NHID + n0 + cc];
    }
    __syncthreads();
    #pragma unroll
    for (int c = 0; c < 16; ++c) {
        const int flat = c * 256 + tid;
        const int r = flat >> 6, cc = flat & 63;
        wt[(size_t)(z * 1024 + n0 + r) * NHID + k0 + cc] = f2b(t[cc][r]);
    }
}

// ---------------------------------------------------------------------------
// Fused GEMM, bf16 MFMA, 128x128 tile, 256 thr (4 waves, 64x64 acc each).
// K-loop: BK=32, 3-slot rotating LDS pipeline, COUNTED vmcnt (T3/T4): stage
// tile t+2 at top of iteration t, compute tile t, vmcnt(4) certifies tile
// t+1 while t+2's loads stay in flight ACROSS the raw barrier. No vmcnt(0)
// drain in the loop. LDS 48 KB -> 3 blocks/CU.
// tx < 16 : q/k tiles  C = HS . W^T  (fused bias + table-RoPE)
// tx >= 16: v^T tiles  C = Wv^T . HS^T (fused bias), V stored [b][h][d][s].
// XCD-rectangle swizzle kept from R2 (FETCH 42->35 MB measured).
// ---------------------------------------------------------------------------
__global__ __launch_bounds__(256) void fused_gemm_kernel(
    const unsigned short* __restrict__ hsb,   // [4096][1024] bf16
    const unsigned short* __restrict__ wt,    // [3072][1024] bf16  ([n][k])
    const float2* __restrict__ cs,            // [1024][32] (cos,sin)
    const float* __restrict__ bq, const float* __restrict__ bk,
    const float* __restrict__ bv,
    unsigned short* __restrict__ qkv)
{
    __shared__ short SH[24576];      // 48 KB: 3 slots x (A[128][32] | B[128][32])
                                     // epilogue reuses [0,16896) as E[128][132]

    const int tid  = threadIdx.x;
    const int lane = tid & 63;
    const int wv   = __builtin_amdgcn_readfirstlane(tid >> 6);   // 0..3

    // ---- XCD-rectangle swizzle: dispatch-linear -> (tx,ty) ----
    const int hw  = blockIdx.x + 24 * blockIdx.y;   // 0..767, xcd ~ hw%8
    const int xcd = hw & 7;
    const int j   = hw >> 3;                        // 0..95 within XCD
    const int tx  = (xcd & 1) * 12 + (j % 12);      // 0..23
    const int ty  = (xcd >> 1) * 8 + (j / 12);      // 0..31

    const bool vmode = (tx >= 16);

    const unsigned short* Amat;
    const unsigned short* Bmat;
    int a_base, b_base, m0, n0, vb_ = 0;
    if (!vmode) {
        n0 = tx * 128;                       // 0..2047 (q,k planes)
        m0 = ty * 128;                       // hs rows
        Amat = hsb;  a_base = m0;
        Bmat = wt;   b_base = n0;
    } else {
        m0  = (tx - 16) * 128;               // v-channel rows 0..1023
        vb_ = ty >> 3;                       // batch
        n0  = (ty & 7) * 128;                // s
        Amat = wt;   a_base = 2048 + m0;
        Bmat = hsb;  b_base = vb_ * 1024 + n0;
    }

    // ---- staging addressing: wave wv covers rows {16wv..16wv+15, +64} of
    //      A and B per tile. lane i -> row (i>>2); global k-chunk is
    //      pre-swizzled: c = (i&3) ^ ((i>>3)&3)  (LDS dest stays linear).
    const int srow = lane >> 2;                          // 0..15
    const int skc  = ((lane & 3) ^ ((lane >> 3) & 3)) * 8;
    const unsigned short* gA1 = Amat + (size_t)(a_base + 16 * wv + srow) * NHID + skc;
    const unsigned short* gA2 = gA1 + (size_t)64 * NHID;
    const unsigned short* gB1 = Bmat + (size_t)(b_base + 16 * wv + srow) * NHID + skc;
    const unsigned short* gB2 = gB1 + (size_t)64 * NHID;

    // slot layout (shorts): slot*8192 + [A: row*32 + c'*8 | B: 4096 + ...]
#define STAGE(S, T) do { \
    short* Sb_ = SH + (S) * 8192 + 512 * wv; \
    const size_t ko_ = (size_t)(T) * 32; \
    gload16(gA1 + ko_, Sb_); \
    gload16(gA2 + ko_, Sb_ + 2048); \
    gload16(gB1 + ko_, Sb_ + 4096); \
    gload16(gB2 + ko_, Sb_ + 6144); \
} while (0)

    // ---- fragment read addresses ----
    const int R  = (wv & 1) * 64;
    const int CW = (wv >> 1) * 64;
    const int c0 = lane & 15;
    const int g  = lane >> 4;
    const int swz  = (g ^ ((c0 >> 1) & 3)) * 8;    // chunk swizzle (shorts)
    const int aofl = (R + c0) * 32 + swz;
    const int bofl = 4096 + (CW + c0) * 32 + swz;

    f32x4 acc[4][4] = {};

#define COMP(S) do { \
    const short* Sc_ = SH + (S) * 8192; \
    bf16x8 af[4], bfr[4]; \
    _Pragma("unroll") \
    for (int i_ = 0; i_ < 4; ++i_) af[i_]  = *(const bf16x8*)&Sc_[aofl + 512 * i_]; \
    _Pragma("unroll") \
    for (int j_ = 0; j_ < 4; ++j_) bfr[j_] = *(const bf16x8*)&Sc_[bofl + 512 * j_]; \
    __builtin_amdgcn_s_setprio(1); \
    _Pragma("unroll") \
    for (int i_ = 0; i_ < 4; ++i_) \
        _Pragma("unroll") \
        for (int j_ = 0; j_ < 4; ++j_) \
            acc[i_][j_] = __builtin_amdgcn_mfma_f32_16x16x32_bf16( \
                af[i_], bfr[j_], acc[i_][j_], 0, 0, 0); \
    __builtin_amdgcn_s_setprio(0); \
} while (0)

    // ---- K-loop: 32 tiles of BK=32, 3-slot rotation, counted vmcnt ----
    STAGE(0, 0);
    STAGE(1, 1);
    VMWAIT(4);                       // tile 0 landed (tile 1's 4 in flight)
    SBAR();

    #pragma unroll 1
    for (int tb = 0; tb < 30; tb += 3) {
        STAGE(2, tb + 2); COMP(0); VMWAIT(4); SBAR();   // t = tb
        STAGE(0, tb + 3); COMP(1); VMWAIT(4); SBAR();   // t = tb+1
        STAGE(1, tb + 4); COMP(2); VMWAIT(4); SBAR();   // t = tb+2
    }
    // t = 30 (slot 0): nothing left to stage; certify tile 31
    COMP(0); VMWAIT(0); SBAR();
    // t = 31 (slot 1)
    COMP(1);
#undef STAGE
#undef COMP

    // ---- epilogue: compute (bit-identical), restage via LDS [128][132] ----
    __syncthreads();                 // all waves done reading slots
    unsigned short* E = (unsigned short*)SH;
    const int qrow4 = g * 4;

    if (!vmode) {
        const int z  = n0 >> 10;
        const int hd = ((n0 & 1023) + CW) >> 6;
        const float* __restrict__ bb = (z == 0) ? bq : bk;
        const float b0 = bb[hd * 64 + c0];
        const float b1 = bb[hd * 64 + c0 + 16];
        const float b2 = bb[hd * 64 + c0 + 32];
        const float b3 = bb[hd * 64 + c0 + 48];

        #pragma unroll
        for (int i = 0; i < 4; ++i) {
            #pragma unroll
            for (int r = 0; r < 4; ++r) {
                const int ml = R + qrow4 + 16 * i + r;      // local row
                const int s  = (m0 + ml) & 1023;
                float o0 = acc[i][0][r] + b0;
                float o1 = acc[i][1][r] + b1;
                float o2 = acc[i][2][r] + b2;
                float o3 = acc[i][3][r] + b3;
                const float2 cs0 = cs[s * 32 + c0];
                const float2 cs1 = cs[s * 32 + c0 + 16];
                unsigned short* e = E + ml * 132 + CW + c0;
                e[0]  = f2b(o0 * cs0.x - o2 * cs0.y);
                e[16] = f2b(o1 * cs1.x - o3 * cs1.y);
                e[32] = f2b(o2 * cs0.x + o0 * cs0.y);
                e[48] = f2b(o3 * cs1.x + o1 * cs1.y);
            }
        }
        __syncthreads();             // E complete

        const int hd0 = (n0 & 1023) >> 6;
        unsigned short* __restrict__ base = qkv + (size_t)z * QKV_PLANE;
        #pragma unroll
        for (int c = 0; c < 8; ++c) {
            const int chunk = c * 256 + tid;   // 0..2047
            const int row   = chunk >> 4;      // local m
            const int col16 = chunk & 15;      // 16B chunk within row
            const int m     = m0 + row;
            const int bidx  = m >> 10;
            const int s     = m & 1023;
            const int head  = hd0 + (col16 >> 3);
            const int d     = (col16 & 7) * 8;
            u16x8 v = *(const u16x8*)&E[row * 132 + col16 * 8];
            *(u16x8*)&base[(((size_t)bidx * NH + head) * NS + s) * NDH + d] = v;
        }
    } else {
        #pragma unroll
        for (int i = 0; i < 4; ++i) {
            #pragma unroll
            for (int r = 0; r < 4; ++r) {
                const int ml  = R + qrow4 + 16 * i + r;     // local d-channel
                const float bvm = bv[m0 + ml];
                unsigned short* e = E + ml * 132 + CW + c0;
                e[0]  = f2b(acc[i][0][r] + bvm);
                e[16] = f2b(acc[i][1][r] + bvm);
                e[32] = f2b(acc[i][2][r] + bvm);
                e[48] = f2b(acc[i][3][r] + bvm);
            }
        }
        __syncthreads();             // E complete

        unsigned short* __restrict__ vplane = qkv + 2 * (size_t)QKV_PLANE;
        #pragma unroll
        for (int c = 0; c < 8; ++c) {
            const int chunk = c * 256 + tid;
            const int row   = chunk >> 4;      // local d-channel
            const int col16 = chunk & 15;      // s chunk
            u16x8 v = *(const u16x8*)&E[row * 132 + col16 * 8];
            *(u16x8*)&vplane[((size_t)(vb_ * 1024 + m0 + row)) * NS
                             + n0 + col16 * 8] = v;
        }
    }
}

// ---------------------------------------------------------------------------
// Flash attention, bf16 MFMA. Block = 512 thr (8 waves), Q-tile 128 rows of
// one (b,h); wave w owns qrows [w*16, w*16+16). K-tile 64 keys.
// grid 512 blocks -> 2 blocks/CU = 16 waves/CU.
// K/V LDS double-buffered 2-phase pipeline + setprio + XCD swizzle (each XCD
// owns 8 (b,h) pairs x all 8 q-tiles -> K/V set 4 MB/XCD).
// This is the best-measured attn variant (R5 = 149.0us total); the later
// 3-slot, reg-mask, and x16-PV variants each measured lateral-to-negative.
// ---------------------------------------------------------------------------
__global__ __launch_bounds__(512) void attn_kernel(
    const unsigned short* __restrict__ qkv, const float* __restrict__ mask,
    float* __restrict__ out)
{
    // ---- XCD swizzle: dispatch-linear -> (qt, h, b) ----
    const int hw  = blockIdx.x + 8 * (blockIdx.y + 16 * blockIdx.z); // 0..511
    const int xcd = hw & 7;
    const int j   = hw >> 3;             // 0..63 within XCD
    const int hb  = xcd * 8 + (j & 7);   // 0..63: 8 (b,h) pairs per XCD
    const int qt  = j >> 3;              // 0..7
    const int h   = hb & 15, b = hb >> 4;

    const unsigned short* qp  = qkv + ((size_t)(b * NH + h) * NS) * NDH;      // [s][d]
    const unsigned short* kp  = qp + QKV_PLANE;                               // [s][d]
    const unsigned short* vtp = qkv + 2 * (size_t)QKV_PLANE
                              + ((size_t)(b * NH + h) * NDH) * NS;            // [d][s]

    __shared__ unsigned short KsA[2][64 * 64]; // 2x8 KB swizzled [key][dchunk]
    __shared__ unsigned short VtA[2][64 * 64]; // 2x8 KB swizzled [d][keychunk]
    __shared__ unsigned short PsA[128 * 64];   // 16 KB swizzled [qrow][keychunk]
    __shared__ float Mk[1024];                 // mask * log2e
    __shared__ float Ll[128];                  // row sums

    const int tid  = threadIdx.x;
    const int lane = tid & 63;
    const int w    = __builtin_amdgcn_readfirstlane(tid >> 6);   // 0..7
    const int c0   = lane & 15;
    const int g    = lane >> 4;          // 0..3
    const int sw7  = c0 & 7;
    const float C1 = 0.125f * 1.44269504f;

    // ---- mask * log2e -> LDS ----
    {
        const int i = tid * 2;
        float2 mv = *(const float2*)&mask[(size_t)b * NS + i];
        Mk[i]     = mv.x * 1.44269504f;
        Mk[i + 1] = mv.y * 1.44269504f;
    }

    // ---- Q fragments (B-operand, loop-invariant), qrow = qt*128+w*16+c0 ----
    bf16x8 qf[2];
    #pragma unroll
    for (int ks = 0; ks < 2; ++ks)
        qf[ks] = *(const bf16x8*)&qp[
            (size_t)(qt * 128 + w * 16 + c0) * NDH + g * 8 + ks * 32];

    // ---- staging: wave w stages K chunk w and V chunk w (1 KB each) ----
    const int i8 = lane >> 3, c8 = lane & 7;
    const int gsw = (c8 ^ i8) * 8;                   // swizzled element offset
    const unsigned short* gk0 = kp  + (size_t)(w * 8 + i8) * NDH + gsw;
    const unsigned short* gv0 = vtp + (size_t)(w * 8 + i8) * NS  + gsw;

    // ---- loop-invariant LDS addresses (shorts) ----
    int kaddr[4][2], pw4[4], pr[2];
    #pragma unroll
    for (int mt = 0; mt < 4; ++mt)
        #pragma unroll
        for (int ks = 0; ks < 2; ++ks)
            kaddr[mt][ks] = (mt * 16 + c0) * 64 + ((g + ks * 4) ^ sw7) * 8;
    #pragma unroll
    for (int mt = 0; mt < 4; ++mt)
        pw4[mt] = (w * 16 + c0) * 64 + ((2 * mt + (g >> 1)) ^ sw7) * 8 + (g & 1) * 4;
    #pragma unroll
    for (int ks = 0; ks < 2; ++ks)
        pr[ks] = (w * 16 + c0) * 64 + ((g + ks * 4) ^ sw7) * 8;

    // ---- prologue: stage tile 0 into buffer 0 ----
    gload16(gk0, &KsA[0][w * 512]);
    gload16(gv0, &VtA[0][w * 512]);
    __syncthreads();     // drains vmcnt+lgkm: tile0 landed, Mk visible

    // ---- uniform tile bound: skip fully-masked tiles (mask monotone) ----
    int ktmax = 16;
    while (ktmax > 1 && Mk[(ktmax - 1) * 64] < -1.0f) --ktmax;

    float lrow = 0.f;
    f32x4 O[4] = {};

    for (int kt = 0; kt < ktmax; ++kt) {
        const int cur = kt & 1;

        // ---- issue next-tile stage into the other buffer (async) ----
        if (kt + 1 < ktmax) {
            gload16(gk0 + (size_t)(kt + 1) * 64 * NDH, &KsA[cur ^ 1][w * 512]);
            gload16(gv0 + (size_t)(kt + 1) * 64,       &VtA[cur ^ 1][w * 512]);
        }

        const unsigned short* Kb = KsA[cur];
        const unsigned short* Vb = VtA[cur];

        // ---- S^T = K . Q^T  (8 MFMA) ----
        bf16x8 kf[4][2];
        #pragma unroll
        for (int mt = 0; mt < 4; ++mt)
            #pragma unroll
            for (int ks = 0; ks < 2; ++ks)
                kf[mt][ks] = *(const bf16x8*)&Kb[kaddr[mt][ks]];
        f32x4 S[4];
        __builtin_amdgcn_s_setprio(1);
        #pragma unroll
        for (int mt = 0; mt < 4; ++mt) {
            f32x4 a = {};
            a = __builtin_amdgcn_mfma_f32_16x16x32_bf16(kf[mt][0], qf[0], a, 0, 0, 0);
            a = __builtin_amdgcn_mfma_f32_16x16x32_bf16(kf[mt][1], qf[1], a, 0, 0, 0);
            S[mt] = a;
        }
        __builtin_amdgcn_s_setprio(0);

        // ---- softmax numerator: p = exp2(S*C1 + mask2), write P ----
        float psum = 0.f;
        #pragma unroll
        for (int mt = 0; mt < 4; ++mt) {
            float4 mv = *(const float4*)&Mk[kt * 64 + mt * 16 + g * 4];
            float p0 = fexp2(S[mt][0] * C1 + mv.x);
            float p1 = fexp2(S[mt][1] * C1 + mv.y);
            float p2 = fexp2(S[mt][2] * C1 + mv.z);
            float p3 = fexp2(S[mt][3] * C1 + mv.w);
            psum += (p0 + p1) + (p2 + p3);
            uint2 u;
            u.x = f2b2(p0, p1);
            u.y = f2b2(p2, p3);
            *(uint2*)&PsA[pw4[mt]] = u;    // ds_write_b64, wave-private row
        }
        lrow += psum;

        // ---- O += P . V  (8 MFMA) ----
        bf16x8 pf[2], vf[4][2];
        #pragma unroll
        for (int ks = 0; ks < 2; ++ks)
            pf[ks] = *(const bf16x8*)&PsA[pr[ks]];
        #pragma unroll
        for (int nd = 0; nd < 4; ++nd)
            #pragma unroll
            for (int ks = 0; ks < 2; ++ks)
                vf[nd][ks] = *(const bf16x8*)&Vb[kaddr[nd][ks]];
        __builtin_amdgcn_s_setprio(1);
        #pragma unroll
        for (int nd = 0; nd < 4; ++nd) {
            f32x4 o = O[nd];
            o = __builtin_amdgcn_mfma_f32_16x16x32_bf16(pf[0], vf[nd][0], o, 0, 0, 0);
            o = __builtin_amdgcn_mfma_f32_16x16x32_bf16(pf[1], vf[nd][1], o, 0, 0, 0);
            O[nd] = o;
        }
        __builtin_amdgcn_s_setprio(0);

        // single per-tile join: drains this wave's outstanding stage loads
        // (vmcnt) and guarantees all waves finished reading buf[cur] before
        // it is overwritten next iteration.
        __syncthreads();
    }

    // ---- final l reduction + normalize + store ----
    lrow += __shfl_xor(lrow, 16);
    lrow += __shfl_xor(lrow, 32);
    if (g == 0) Ll[w * 16 + c0] = lrow;    // same-wave LDS, no barrier needed
    float4 lv4 = *(const float4*)&Ll[w * 16 + g * 4];
    float inv[4];
    #pragma unroll
    for (int r = 0; r < 4; ++r) inv[r] = 1.0f / ((const float*)&lv4)[r];

    #pragma unroll
    for (int nd = 0; nd < 4; ++nd)
        #pragma unroll
        for (int r = 0; r < 4; ++r) {
            const int row = qt * 128 + w * 16 + g * 4 + r;
            const int col = h * 64 + nd * 16 + c0;
            out[((size_t)b * NS + row) * NHID + col] = O[nd][r] * inv[r];
        }
}

// ---------------------------------------------------------------------------
extern "C" void kernel_launch(void* const* d_in, const int* in_sizes, int n_in,
                              void* d_out, int out_size, void* d_ws, size_t ws_size,
                              hipStream_t stream) {
    const float* hs    = (const float*)d_in[0];
    const float* mask  = (const float*)d_in[1];
    const float* freqs = (const float*)d_in[2];
    const float* Wq    = (const float*)d_in[3];
    const float* bq    = (const float*)d_in[4];
    const float* Wk    = (const float*)d_in[5];
    const float* bk    = (const float*)d_in[6];
    const float* Wv    = (const float*)d_in[7];
    const float* bv    = (const float*)d_in[8];
    float* out = (float*)d_out;

    // workspace: qkv bf16 25.2MB | hsb bf16 8.4MB | wt bf16 6.3MB | cs 256KB
    char* ws = (char*)d_ws;
    unsigned short* qkvb = (unsigned short*)ws;
    unsigned short* hsb  = (unsigned short*)(ws + 25165824);
    unsigned short* wtb  = (unsigned short*)(ws + 33554432);
    float2*         csb  = (float2*)       (ws + 39845888);

    prep_kernel<<<dim3(16, 16, 5), 256, 0, stream>>>(hs, freqs, Wq, Wk, Wv,
                                                     hsb, wtb, csb);
    fused_gemm_kernel<<<dim3(24, 32), 256, 0, stream>>>(hsb, wtb, csb,
                                                        bq, bk, bv, qkvb);
    attn_kernel<<<dim3(NS / 128, NH, NB), 512, 0, stream>>>(qkvb, mask, out);
}